// Round 1
// baseline (387.061 us; speedup 1.0000x reference)
//
#include <hip/hip_runtime.h>

#define N_ 128
#define C_ 64
#define O_ 64
#define R_ 8
#define T_ 128
#define V_ 25
#define TV_ 3200   // T_*V_
#define EPS_ 1e-5f
#define G_ 4       // c-group per block in k5

// ---------------- K1: xs[n,i,v] = sum_t x[n,i,t,v] ----------------
__global__ __launch_bounds__(256) void k1_colsum(const float* __restrict__ x,
                                                 float* __restrict__ xs) {
    int ni = blockIdx.x;                       // n*C_ + i
    const float* xp = x + (size_t)ni * TV_;
    int tid = threadIdx.x;
    __shared__ float part[200];
    if (tid < 200) {
        float s = 0.f;
        #pragma unroll
        for (int k = 0; k < 16; ++k) s += xp[tid + 200 * k];
        part[tid] = s;                          // part[g*25+v], t = g + 8k
    }
    __syncthreads();
    if (tid < V_) {
        float t = 0.f;
        #pragma unroll
        for (int g = 0; g < 8; ++g) t += part[g * 25 + tid];
        xs[ni * V_ + tid] = t;
    }
}

// ---------------- K2: x1,x2 -> rel2[n,o,u,v] ----------------
__global__ __launch_bounds__(256) void k2_rel(const float* __restrict__ xs,
        const float* __restrict__ w1, const float* __restrict__ b1,
        const float* __restrict__ w2, const float* __restrict__ b2,
        const float* __restrict__ w4, const float* __restrict__ b4,
        const float* __restrict__ A, const float* __restrict__ alpha,
        float* __restrict__ rel2) {
    int n = blockIdx.x;
    int tid = threadIdx.x;
    __shared__ float x1s[R_][V_];
    __shared__ float x2s[R_][V_];
    __shared__ float rels[R_ * 625];
    const float invT = 1.0f / (float)T_;
    if (tid < 200) {
        int r = tid / 25, v = tid % 25;
        float a1 = b1[r], a2 = b2[r];
        for (int i = 0; i < C_; ++i) {
            float xm = xs[(n * C_ + i) * V_ + v] * invT;
            a1 += w1[r * C_ + i] * xm;
            a2 += w2[r * C_ + i] * xm;
        }
        x1s[r][v] = a1;
        x2s[r][v] = a2;
    }
    __syncthreads();
    for (int idx = tid; idx < R_ * 625; idx += 256) {
        int r = idx / 625, uv = idx % 625;
        int u = uv / 25, v = uv % 25;
        rels[idx] = tanhf(x1s[r][u] - x2s[r][v]);
    }
    __syncthreads();
    float al = alpha[0];
    for (int idx = tid; idx < O_ * 625; idx += 256) {
        int o = idx / 625, uv = idx % 625;
        float acc = b4[o];
        #pragma unroll
        for (int r = 0; r < R_; ++r) acc += w4[o * R_ + r] * rels[r * 625 + uv];
        rel2[(size_t)n * O_ * 625 + idx] = acc * al + A[uv];
    }
}

// ---------------- K3: x3[n,r,t,v] = sum_i w5[r,i]*x[n,i,t,v] + b5[r] ----------------
__global__ __launch_bounds__(256) void k3_x3(const float* __restrict__ x,
        const float* __restrict__ w5, const float* __restrict__ b5,
        float* __restrict__ x3) {
    __shared__ float w5s[R_ * C_];
    int tid = threadIdx.x;
    w5s[tid] = w5[tid];
    w5s[tid + 256] = w5[tid + 256];
    __syncthreads();
    int gid = blockIdx.x * 256 + tid;          // grid = 409600/256 = 1600 exact
    int n = gid / TV_, p = gid % TV_;
    float acc[R_];
    #pragma unroll
    for (int r = 0; r < R_; ++r) acc[r] = b5[r];
    const float* xp = x + (size_t)n * C_ * TV_ + p;
    for (int i = 0; i < C_; ++i) {
        float xv = xp[(size_t)i * TV_];
        #pragma unroll
        for (int r = 0; r < R_; ++r) acc[r] += w5s[r * C_ + i] * xv;
    }
    float* x3p = x3 + (size_t)n * R_ * TV_ + p;
    #pragma unroll
    for (int r = 0; r < R_; ++r) x3p[(size_t)r * TV_] = acc[r];
}

// ---------------- K4: RouteFuncMLP -> rf[n,r,t] ----------------
__global__ __launch_bounds__(256) void k4_route(const float* __restrict__ x3,
        const float* __restrict__ g_w, const float* __restrict__ g_b,
        const float* __restrict__ a_w, const float* __restrict__ a_b,
        const float* __restrict__ bn_g, const float* __restrict__ bn_b,
        const float* __restrict__ bn_rm, const float* __restrict__ bn_rv,
        const float* __restrict__ rf_bw, float* __restrict__ rf) {
    int n = blockIdx.x, tid = threadIdx.x;
    __shared__ float ps[R_][T_];
    __shared__ float hs[R_][T_];
    __shared__ float gs[R_];
    __shared__ float ggs[R_];
    // p[r,t] = mean_v x3
    for (int idx = tid; idx < R_ * T_; idx += 256) {
        int r = idx / T_, t = idx % T_;
        const float* xp = x3 + ((size_t)n * R_ + r) * TV_ + t * V_;
        float s = 0.f;
        #pragma unroll
        for (int v = 0; v < V_; ++v) s += xp[v];
        ps[r][t] = s * (1.0f / V_);
    }
    __syncthreads();
    // g[r] = mean_t p
    if (tid < R_) {
        float s = 0.f;
        for (int t = 0; t < T_; ++t) s += ps[tid][t];
        gs[tid] = s * (1.0f / T_);
    }
    __syncthreads();
    // gg = g_w @ g + g_b
    if (tid < R_) {
        float a = g_b[tid];
        #pragma unroll
        for (int i = 0; i < R_; ++i) a += g_w[tid * R_ + i] * gs[i];
        ggs[tid] = a;
    }
    __syncthreads();
    // h = relu(bn(tconv(p+gg, a_w) + a_b))
    for (int idx = tid; idx < R_ * T_; idx += 256) {
        int r = idx / T_, t = idx % T_;
        float acc = a_b[r];
        #pragma unroll
        for (int i = 0; i < R_; ++i) {
            #pragma unroll
            for (int k = 0; k < 3; ++k) {
                int tt = t + k - 1;
                if (tt >= 0 && tt < T_)
                    acc += a_w[(r * R_ + i) * 3 + k] * (ps[i][tt] + ggs[i]);
            }
        }
        float sc = bn_g[r] * rsqrtf(bn_rv[r] + EPS_);
        float h = (acc - bn_rm[r]) * sc + bn_b[r];
        hs[r][t] = fmaxf(h, 0.f);
    }
    __syncthreads();
    // rf = tconv(h, rf_bw) + 1
    for (int idx = tid; idx < R_ * T_; idx += 256) {
        int r = idx / T_, t = idx % T_;
        float acc = 1.0f;
        #pragma unroll
        for (int i = 0; i < R_; ++i) {
            #pragma unroll
            for (int k = 0; k < 3; ++k) {
                int tt = t + k - 1;
                if (tt >= 0 && tt < T_)
                    acc += rf_bw[(r * R_ + i) * 3 + k] * hs[i][tt];
            }
        }
        rf[((size_t)n * R_ + r) * T_ + t] = acc;
    }
}

// ---------------- K5: out[n,c,t,u] = sum_v rel2[n,c,u,v] * z[n,c,t,v] ----------------
// z[n,c,t,v] = b3[c] + sum_r w3[c,r]*rf[n,r,t]*x3[n,r,t,v]
__global__ __launch_bounds__(256) void k5_out(const float* __restrict__ x3,
        const float* __restrict__ rf, const float* __restrict__ rel2,
        const float* __restrict__ w3, const float* __restrict__ b3,
        float* __restrict__ out) {
    int n = blockIdx.x / (O_ / G_);
    int c0 = (blockIdx.x % (O_ / G_)) * G_;
    int tid = threadIdx.x;
    __shared__ float rfs[R_][T_];
    __shared__ float zs[G_][TV_];
    for (int idx = tid; idx < R_ * T_; idx += 256)
        rfs[idx / T_][idx % T_] = rf[(size_t)n * R_ * T_ + idx];
    float w3s[G_][R_];
    float b3s[G_];
    #pragma unroll
    for (int cl = 0; cl < G_; ++cl) {
        b3s[cl] = b3[c0 + cl];
        #pragma unroll
        for (int r = 0; r < R_; ++r) w3s[cl][r] = w3[(c0 + cl) * R_ + r];
    }
    __syncthreads();
    // phase A: z tiles for the whole c-group, reading x3 once
    const float* x3p = x3 + (size_t)n * R_ * TV_;
    for (int p = tid; p < TV_; p += 256) {
        int t = p / V_;
        float xv[R_];
        #pragma unroll
        for (int r = 0; r < R_; ++r) xv[r] = x3p[(size_t)r * TV_ + p] * rfs[r][t];
        #pragma unroll
        for (int cl = 0; cl < G_; ++cl) {
            float acc = b3s[cl];
            #pragma unroll
            for (int r = 0; r < R_; ++r) acc += w3s[cl][r] * xv[r];
            zs[cl][p] = acc;
        }
    }
    __syncthreads();
    // phase B: per-thread (t-half, c_local, u); rel row in registers
    if (tid < 200) {
        int th = tid / 100, rem = tid % 100;
        int cl = rem / 25, u = rem % 25;
        float relr[V_];
        const float* rp = rel2 + (((size_t)n * O_ + c0 + cl) * V_ + u) * V_;
        #pragma unroll
        for (int v = 0; v < V_; ++v) relr[v] = rp[v];
        float* op = out + ((size_t)n * O_ + c0 + cl) * T_ * V_ + u;
        int t0 = th * (T_ / 2);
        for (int t = t0; t < t0 + T_ / 2; ++t) {
            float acc = 0.f;
            #pragma unroll
            for (int v = 0; v < V_; ++v) acc += zs[cl][t * V_ + v] * relr[v];
            op[t * V_] = acc;
        }
    }
}

extern "C" void kernel_launch(void* const* d_in, const int* in_sizes, int n_in,
                              void* d_out, int out_size, void* d_ws, size_t ws_size,
                              hipStream_t stream) {
    const float* x     = (const float*)d_in[0];
    const float* A     = (const float*)d_in[1];
    const float* alpha = (const float*)d_in[2];
    const float* w1    = (const float*)d_in[3];
    const float* b1    = (const float*)d_in[4];
    const float* w2    = (const float*)d_in[5];
    const float* b2    = (const float*)d_in[6];
    const float* w5    = (const float*)d_in[7];
    const float* b5    = (const float*)d_in[8];
    const float* w3    = (const float*)d_in[9];
    const float* b3    = (const float*)d_in[10];
    const float* w4    = (const float*)d_in[11];
    const float* b4    = (const float*)d_in[12];
    const float* g_w   = (const float*)d_in[13];
    const float* g_b   = (const float*)d_in[14];
    const float* a_w   = (const float*)d_in[15];
    const float* a_b   = (const float*)d_in[16];
    const float* bn_g  = (const float*)d_in[17];
    const float* bn_b  = (const float*)d_in[18];
    const float* bn_rm = (const float*)d_in[19];
    const float* bn_rv = (const float*)d_in[20];
    const float* rf_bw = (const float*)d_in[21];
    float* out = (float*)d_out;
    float* ws  = (float*)d_ws;

    float* xs   = ws;                          // 204,800 floats
    float* rel2 = ws + 204800;                 // 5,120,000 floats
    float* x3   = ws + 204800 + 5120000;       // 3,276,800 floats
    float* rf   = x3 + 3276800;                // 131,072 floats

    hipLaunchKernelGGL(k1_colsum, dim3(N_ * C_), dim3(256), 0, stream, x, xs);
    hipLaunchKernelGGL(k2_rel, dim3(N_), dim3(256), 0, stream,
                       xs, w1, b1, w2, b2, w4, b4, A, alpha, rel2);
    hipLaunchKernelGGL(k3_x3, dim3(1600), dim3(256), 0, stream, x, w5, b5, x3);
    hipLaunchKernelGGL(k4_route, dim3(N_), dim3(256), 0, stream,
                       x3, g_w, g_b, a_w, a_b, bn_g, bn_b, bn_rm, bn_rv, rf_bw, rf);
    hipLaunchKernelGGL(k5_out, dim3(N_ * (O_ / G_)), dim3(256), 0, stream,
                       x3, rf, rel2, w3, b3, out);
}